// Round 1
// baseline (58.461 us; speedup 1.0000x reference)
//
#include <hip/hip_runtime.h>
#include <hip/hip_bf16.h>

// AttnNet_50852412784797
//
// The reference network is mathematically the identity on Ec:
//   alpha = softmax(Sc, axis=-2)  sums to 1 over l2,
//   attn_i = alpha * Ec[..., None, :]  uses Ec indexed by l1 (NOT l2),
//   attn = sum_{l2} alpha * Ec[b,s,l1,:] = Ec[b,s,l1,:].
// The final reshape (B,S,1,L*D) has the same row-major flat layout as
// Ec's (B,S,L,D). So the optimal kernel is a flat copy of Ec -> out.
//
// B=4, S=16, L=128, D=64 -> 524288 fp32 elements = 131072 float4.

__global__ __launch_bounds__(256) void AttnNet_identity_copy(
    const float4* __restrict__ in, float4* __restrict__ out, int n4) {
    int i = blockIdx.x * blockDim.x + threadIdx.x;
    if (i < n4) out[i] = in[i];
}

extern "C" void kernel_launch(void* const* d_in, const int* in_sizes, int n_in,
                              void* d_out, int out_size, void* d_ws, size_t ws_size,
                              hipStream_t stream) {
    const float4* Ec = (const float4*)d_in[0];   // (B,S,L,D) fp32, 524288 elements
    float4* out = (float4*)d_out;                // (B,S,1,L*D) fp32, same flat layout

    const int n4 = out_size / 4;                 // 131072 float4
    const int block = 256;
    const int grid = (n4 + block - 1) / block;   // 512 blocks
    AttnNet_identity_copy<<<grid, block, 0, stream>>>(Ec, out, n4);
}